// Round 13
// baseline (443.531 us; speedup 1.0000x reference)
//
#include <hip/hip_runtime.h>
#include <hip/hip_fp16.h>

// Weight-stationary LSTM classifier — WAVE-AUTONOMOUS sync (round 13).
// No per-step __syncthreads: flags are per-(wg,wave) [19 wgs x 16 waves = 304
// words/group, packed]. Producer wave: s_waitcnt vmcnt(0) -> lane0 relaxed
// flag store (release if XCD vote failed). Consumer wave: 64 lanes poll all
// 304 flags (5 contiguous 256B loads + __all), no barrier. 2432 wave
// pipelines self-timed; skew bounded at 1 step by flag deps.
// Geometry unchanged from R12: B=4096, 8 groups(512 rows) x 19 wgs(16jh x 4g),
// grid 152, 1024 thr; W fragment-blocked in LDS (conflict-free); exchange
// panels in MFMA-fragment swizzle; xpart before wait; virgin-slot rotation
// with acquire-fence on reuse; stage_x 3-ahead AFTER flag when depth>=6
// (embed gather off critical path), else 2-ahead before flag (R12 order).
// d_ws: [0,64KB) flags(16KB)+ids, then depth x 5.24MB swizzled slots.

#define TT 22
#define STEPS 22
#define NB 19
#define NGRP 8
#define GROWS 512
#define NWG (NB * NGRP)          // 152
#define NTHR 1024
#define NWAVE 16
#define KTOT 20                  // kt blocks (640 halves)
#define BUFELT ((size_t)256 * KTOT * 512)
#define SROWS 27                 // staging rows per wg (ceil 512/19)
#define NFLG (NB * NWAVE)        // 304 flags per group

typedef _Float16 f16;
typedef _Float16 f16x8 __attribute__((ext_vector_type(8)));
typedef float    f32x4 __attribute__((ext_vector_type(4)));

__device__ __forceinline__ float sigm(float x) { return 1.0f / (1.0f + __expf(-x)); }
__device__ __forceinline__ float tanh_f(float x) {
    float ax = fabsf(x);
    float e = __expf(-2.0f * ax);
    return copysignf((1.0f - e) / (1.0f + e), x);
}
__device__ __forceinline__ f16x8 pack8(float4 a, float4 b) {
    f16x8 v;
    v[0] = (f16)a.x; v[1] = (f16)a.y; v[2] = (f16)a.z; v[3] = (f16)a.w;
    v[4] = (f16)b.x; v[5] = (f16)b.y; v[6] = (f16)b.z; v[7] = (f16)b.w;
    return v;
}

__global__ __launch_bounds__(NTHR, 4)
void lstm_ws(const int* __restrict__ cap, const int* __restrict__ cap_len,
             const float* __restrict__ embed,
             const float* __restrict__ Wih, const float* __restrict__ Whh,
             const float* __restrict__ bih, const float* __restrict__ bhh,
             const float* __restrict__ v_wn, const float* __restrict__ g_wn,
             const float* __restrict__ b_cls,
             f16* __restrict__ bufs, int depth,
             unsigned* __restrict__ bar, float* __restrict__ out)
{
    __shared__ f16 Wl[80 * 512];     // 80 KB fragment-blocked W (4g x 20kt)
    __shared__ int capS[SROWS][TT];
    __shared__ float scaleS[2];

    const int tid = threadIdx.x;
    const int b   = blockIdx.x;
    const int grp = b & 7;
    const int nb  = b >> 3;
    const int mrow0 = grp * GROWS;
    const int wv = tid >> 6, ln = tid & 63, c = ln & 15, kg = ln >> 4;

    unsigned* fbase  = bar + grp * 512;            // 304 flag words (packed)
    unsigned* myflag = fbase + nb * NWAVE + wv;
    unsigned* ids    = bar + 4096;                 // 152 id words

    if (tid == 0)
        (void)__hip_atomic_load(fbase, __ATOMIC_ACQUIRE, __HIP_MEMORY_SCOPE_AGENT);
    unsigned xcc;
    asm volatile("s_getreg_b32 %0, hwreg(HW_REG_XCC_ID)" : "=s"(xcc));
    if (tid == 0)
        __hip_atomic_store(ids + grp * NB + nb, xcc + 1u, __ATOMIC_RELAXED,
                           __HIP_MEMORY_SCOPE_AGENT);

    auto slot = [&](int n) { return bufs + (size_t)(n % depth) * BUFELT; };

    // ---- W -> LDS, fragment-blocked (R12, conflict-free) ----
    for (int u = tid; u < 80 * 64; u += NTHR) {
        int f = u >> 6, l = u & 63;
        int g = f / KTOT, kt = f - g * KTOT;
        int cc = l & 15, kgg = l >> 4;
        int jh0 = nb * 16 + cc;
        int j = g * 300 + jh0;
        int kb = kt * 32 + kgg * 8;
        f16x8 v;
        #pragma unroll
        for (int i = 0; i < 8; ++i) {
            int kk = kb + i;
            float x = 0.f;
            if (jh0 < 300) {
                if (kk < 300)                   x = Wih[(size_t)j * 300 + kk];
                else if (kk >= 320 && kk < 620) x = Whh[(size_t)j * 300 + (kk - 320)];
            }
            v[i] = (f16)x;
        }
        *(f16x8*)&Wl[(size_t)f * 512 + l * 8] = v;
    }

    const int srow0 = nb * SROWS;
    const int nr = (GROWS - srow0) < SROWS ? (GROWS - srow0) : SROWS;  // 27/26
    for (int u = tid; u < SROWS * TT; u += NTHR) {
        int rl = u / TT, t = u - rl * TT;
        if (rl < nr) capS[rl][t] = cap[(size_t)(mrow0 + srow0 + rl) * TT + t];
    }
    if (tid < 2) {
        float s = 0.f;
        for (int k = 0; k < 300; ++k) { float v = v_wn[tid * 300 + k]; s += v * v; }
        scaleS[tid] = g_wn[tid] * rsqrtf(s);
    }
    __syncthreads();   // ONE wg barrier: W/capS/scale ready. None in the loop.

    // ---- x staging into swizzled layout (per-thread items; covered by the
    //      owning wave's flag via its vmcnt drain) ----
    auto stage_x = [&](int t, f16* bufn) {
        for (int u = tid; u < nr * 40; u += NTHR) {
            int rl = u / 40, k8 = u - rl * 40;
            int grow = mrow0 + srow0 + rl;
            const float* er = embed + (size_t)capS[rl][t] * 300;
            int k0 = k8 * 8;
            f16x8 v;
            if (k0 < 296) {
                v = pack8(*(const float4*)(er + k0), *(const float4*)(er + k0 + 4));
            } else if (k0 == 296) {
                float4 a = *(const float4*)(er + 296);
                v[0] = (f16)a.x; v[1] = (f16)a.y; v[2] = (f16)a.z; v[3] = (f16)a.w;
                v[4] = v[5] = v[6] = v[7] = (f16)0.f;
            } else {
                #pragma unroll
                for (int i = 0; i < 8; ++i) v[i] = (f16)0.f;
            }
            size_t off = ((size_t)((grow >> 4) * KTOT + (k8 >> 2))) * 512
                         + (grow & 15) * 32 + (k8 & 3) * 8;
            *(f16x8*)(bufn + off) = v;
        }
    };

    // ---- per-WAVE arrive / wait (no wg barriers) ----
    bool fastp = true;   // set after vote; prologue uses release (safe)
    auto arriveW = [&](unsigned ph, bool rel) {
        if (rel) {
            if (ln == 0)
                __hip_atomic_store(myflag, ph, __ATOMIC_RELEASE,
                                   __HIP_MEMORY_SCOPE_AGENT);
        } else {
            asm volatile("s_waitcnt vmcnt(0)" ::: "memory");
            if (ln == 0)
                __hip_atomic_store(myflag, ph, __ATOMIC_RELAXED,
                                   __HIP_MEMORY_SCOPE_AGENT);
        }
    };
    auto waitW = [&](unsigned ph, bool fen) {
        for (;;) {
            bool ok = true;
            #pragma unroll
            for (int r = 0; r < 5; ++r) {
                int idx = ln + r * 64;
                if (idx < NFLG) {
                    unsigned v = __hip_atomic_load(fbase + idx, __ATOMIC_RELAXED,
                                                   __HIP_MEMORY_SCOPE_AGENT);
                    ok = ok && (v >= ph);
                }
            }
            if (__all(ok)) break;
            __builtin_amdgcn_s_sleep(1);
        }
        if (fen)
            __builtin_amdgcn_fence(__ATOMIC_ACQUIRE, "agent");
        asm volatile("" ::: "memory");   // no compiler reorder across the poll
    };

    // per-lane constants (R12)
    size_t aoff[2];
    #pragma unroll
    for (int m = 0; m < 2; ++m)
        aoff[m] = (size_t)(((mrow0 >> 4) + wv * 2 + m) * KTOT) * 512
                  + c * 32 + kg * 8;
    int wbase[4];
    #pragma unroll
    for (int g = 0; g < 4; ++g) wbase[g] = g * KTOT * 512 + ln * 8;

    const int jh = nb * 16 + c;
    float bias[4];
    #pragma unroll
    for (int g = 0; g < 4; ++g) {
        float bv = 0.f;
        if (jh < 300) { int j = g * 300 + jh; bv = bih[j] + bhh[j]; }
        bias[g] = bv;
    }
    int lenr[2][4];
    #pragma unroll
    for (int m = 0; m < 2; ++m) {
        int rb = mrow0 + wv * 32 + m * 16 + kg * 4;
        #pragma unroll
        for (int rg = 0; rg < 4; ++rg) lenr[m][rg] = cap_len[rb + rg];
    }
    const int hkt  = (320 + jh) >> 5;
    const int hkgd = ((320 + jh) >> 3) & 3;
    const int hel  = jh & 7;

    float cst[2][4] = {};
    float hreg[2][4] = {};
    f32x4 acc[2][4];

    auto xpart = [&](const f16* bufc) {
        #pragma unroll
        for (int kt = 0; kt < 10; ++kt) {
            f16x8 av[2];
            #pragma unroll
            for (int m = 0; m < 2; ++m)
                av[m] = *(const f16x8*)(bufc + aoff[m] + kt * 512);
            #pragma unroll
            for (int g = 0; g < 4; ++g) {
                f16x8 bv = *(const f16x8*)&Wl[wbase[g] + kt * 512];
                #pragma unroll
                for (int m = 0; m < 2; ++m)
                    acc[m][g] = __builtin_amdgcn_mfma_f32_16x16x32_f16(av[m], bv, acc[m][g], 0, 0, 0);
            }
        }
    };
    auto hpart = [&](const f16* bufc) {
        #pragma unroll
        for (int kt = 10; kt < KTOT; ++kt) {
            f16x8 av[2];
            #pragma unroll
            for (int m = 0; m < 2; ++m)
                av[m] = *(const f16x8*)(bufc + aoff[m] + kt * 512);
            #pragma unroll
            for (int g = 0; g < 4; ++g) {
                f16x8 bv = *(const f16x8*)&Wl[wbase[g] + kt * 512];
                #pragma unroll
                for (int m = 0; m < 2; ++m)
                    acc[m][g] = __builtin_amdgcn_mfma_f32_16x16x32_f16(av[m], bv, acc[m][g], 0, 0, 0);
            }
        }
    };

    // staging mode: ah3 (depth>=6) = stage AFTER flag, 3 ahead; ah2 = R12; ah1 serial
    const int ah = (depth >= 6) ? 3 : (depth >= 3 ? 2 : 1);
    stage_x(0, slot(0));                 // slot0 fully memset (h_0=0 + pads)
    if (ah >= 2) stage_x(1, slot(1));
    if (ah == 3) stage_x(2, slot(2));
    arriveW(1, true);                    // release: covers ids + x stages
    waitW(1, false);

    // XCD placement vote (per wave, no barrier; ids covered by flag(1))
    {
        unsigned idv = __hip_atomic_load(ids + grp * NB + (ln < NB ? ln : 0),
                                         __ATOMIC_RELAXED, __HIP_MEMORY_SCOPE_AGENT);
        unsigned id0 = (unsigned)__shfl((int)idv, 0);
        fastp = __all(idv == id0);
    }

    #pragma unroll 1
    for (int t = 0; t < STEPS; ++t) {
        const f16* bufc = slot(t);
        #pragma unroll
        for (int m = 0; m < 2; ++m)
            #pragma unroll
            for (int g = 0; g < 4; ++g) {
                float bv = bias[g];
                f32x4 b4 = {bv, bv, bv, bv};
                acc[m][g] = b4;
            }

        bool reuse = (unsigned)(t + 1) >= (unsigned)depth;
        if (ah >= 2) {
            xpart(bufc);                  // x(t) covered by wait(t) last iter
            waitW((unsigned)(t + 1), reuse);
        } else {
            waitW((unsigned)(t + 1), reuse);
            xpart(bufc);
        }
        hpart(bufc);

        f16* bufn = slot(t + 1);
        #pragma unroll
        for (int m = 0; m < 2; ++m) {
            int rtile = (mrow0 >> 4) + wv * 2 + m;
            size_t hb = ((size_t)(rtile * KTOT + hkt)) * 512 + hkgd * 8 + hel;
            #pragma unroll
            for (int rg = 0; rg < 4; ++rg) {
                bool upd = (t < lenr[m][rg]);
                float iv = sigm(acc[m][0][rg]);
                float fv = sigm(acc[m][1][rg]);
                float gv = tanh_f(acc[m][2][rg]);
                float ov = sigm(acc[m][3][rg]);
                float cn = fv * cst[m][rg] + iv * gv;
                cn = upd ? cn : cst[m][rg];
                cst[m][rg] = cn;
                float hn = ov * tanh_f(cn);
                hreg[m][rg] = upd ? hn : hreg[m][rg];
                f16 hv = (jh < 300) ? (f16)hreg[m][rg] : (f16)0.f;
                bufn[hb + (size_t)(kg * 4 + rg) * 32] = hv;
            }
        }

        if (ah == 2 && t + 2 < STEPS) stage_x(t + 2, slot(t + 2));
        if (ah == 1 && t + 1 < STEPS) stage_x(t + 1, slot(t + 1));
        arriveW((unsigned)(t + 2), !fastp);
        if (ah == 3 && t + 3 < STEPS) stage_x(t + 3, slot(t + 3));  // off-path
    }

    waitW((unsigned)(STEPS + 1), true);

    // ---- head: this wg's staged rows, swizzled h reads ----
    const f16* hb = slot(STEPS);
    for (int u = tid; u < nr * 2; u += NTHR) {
        int rl = u >> 1, cls = u & 1;
        int grow = mrow0 + srow0 + rl;
        float sc = scaleS[cls];
        const float* vr = v_wn + cls * 300;
        size_t rbase = ((size_t)((grow >> 4) * KTOT)) * 512 + (grow & 15) * 32;
        float s = 0.f;
        #pragma unroll 4
        for (int k = 0; k < 300; ++k) {
            int k2 = 320 + k;
            size_t off = rbase + (size_t)(k2 >> 5) * 512 + ((k2 >> 3) & 3) * 8 + (k2 & 7);
            s += vr[k] * (float)hb[off];
        }
        out[(size_t)grow * 2 + cls] = sc * s + b_cls[cls];
    }
}

extern "C" void kernel_launch(void* const* d_in, const int* in_sizes, int n_in,
                              void* d_out, int out_size, void* d_ws, size_t ws_size,
                              hipStream_t stream) {
    const int*   cap     = (const int*)  d_in[0];
    const int*   cap_len = (const int*)  d_in[1];
    const float* embed   = (const float*)d_in[2];
    const float* W_ih    = (const float*)d_in[3];
    const float* W_hh    = (const float*)d_in[4];
    const float* b_ih    = (const float*)d_in[5];
    const float* b_hh    = (const float*)d_in[6];
    const float* v_wn    = (const float*)d_in[7];
    const float* g_wn    = (const float*)d_in[8];
    const float* b_cls   = (const float*)d_in[9];
    float* out = (float*)d_out;

    unsigned* bar = (unsigned*)d_ws;
    f16* bufs = (f16*)((char*)d_ws + 65536);
    size_t slot_bytes = BUFELT * sizeof(f16);          // 5,242,880
    int depth = (int)((ws_size > 65536 ? ws_size - 65536 : 0) / slot_bytes);
    if (depth > STEPS + 1) depth = STEPS + 1;          // 23 = fully virgin
    if (depth < 2) depth = 2;

    hipMemsetAsync(bar, 0, 65536, stream);             // flags + ids
    hipMemsetAsync(bufs, 0, slot_bytes, stream);       // slot 0 (h_0=0 + pads)

    lstm_ws<<<NWG, NTHR, 0, stream>>>(cap, cap_len, embed, W_ih, W_hh, b_ih, b_hh,
                                      v_wn, g_wn, b_cls, bufs, depth, bar, out);
}

// Round 14
// 400.371 us; speedup vs baseline: 1.1078x; 1.1078x over previous
//
#include <hip/hip_runtime.h>
#include <hip/hip_fp16.h>

// Producer/consumer LSTM classifier (round 14). 8 groups (512 rows) x 30 wgs
// = 240 wgs, grp = b&7 (group == XCD), all co-resident (LDS 92KB -> 1 wg/CU).
//   mains (idx 0..18, nb): per step acc = gx(t) + h(t)@Whh (K=320, Whh in
//     LDS frag-blocked), gates, h->slot(t+1); stage x-frag panel x(t+3)
//     AFTER the flag (off critical path). mflag = t+2 after step t.
//   helpers (idx 19..29, j; tiles {j, j+11 if j<8}): gx(tw) = bias +
//     x(tw)@Wih from staged x panel; run ahead of mains; ghflag = tw+2.
// Flag algebra: x(s) ready <=> all mflags >= s; gx(t) ready <=> ghflag >= t+2;
// helper waits mflags >= max(tw,1) (covers x + gx-slot reuse); main h-wait
// mflags >= t+1. gx (GD=4 ring) + helper-x reads via NONTEMPORAL loads (no
// stale L1 on reuse); h ring HD<=23 mostly virgin. Same-XCD relaxed-flag
// fastpath w/ XCC_ID vote, release/acquire fallback (R9-12 proven).
// d_ws: [0,64KB) flags+ids | GD gx slots (9.96MB) | XD x slots (2.62MB) |
//       HD h slots (2.62MB).

#define TT 22
#define STEPS 22
#define NB 19
#define NHELP 11
#define NWG 240
#define NTHR 512
#define KT 10                                   // kt blocks (K=320)
#define SROWS 27
#define GD 4
#define XD 5
#define HSLOT ((size_t)256 * KT * 512)          // f16 elems per h/x slot
#define GXSLOT ((size_t)(8 * 19 * 4 * 32) * 256) // f16 elems per gx slot

typedef _Float16 f16;
typedef _Float16 f16x4 __attribute__((ext_vector_type(4)));
typedef _Float16 f16x8 __attribute__((ext_vector_type(8)));
typedef float    f32x4 __attribute__((ext_vector_type(4)));

__device__ __forceinline__ float sigm(float x) { return 1.0f / (1.0f + __expf(-x)); }
__device__ __forceinline__ float tanh_f(float x) {
    float ax = fabsf(x);
    float e = __expf(-2.0f * ax);
    return copysignf((1.0f - e) / (1.0f + e), x);
}
__device__ __forceinline__ f16x8 pack8(float4 a, float4 b) {
    f16x8 v;
    v[0] = (f16)a.x; v[1] = (f16)a.y; v[2] = (f16)a.z; v[3] = (f16)a.w;
    v[4] = (f16)b.x; v[5] = (f16)b.y; v[6] = (f16)b.z; v[7] = (f16)b.w;
    return v;
}

__global__ __launch_bounds__(NTHR, 2)
void lstm_pc(const int* __restrict__ cap, const int* __restrict__ cap_len,
             const float* __restrict__ embed,
             const float* __restrict__ Wih, const float* __restrict__ Whh,
             const float* __restrict__ bih, const float* __restrict__ bhh,
             const float* __restrict__ v_wn, const float* __restrict__ g_wn,
             const float* __restrict__ b_cls,
             f16* __restrict__ gxb, f16* __restrict__ xb, f16* __restrict__ hbuf,
             int HD, unsigned* __restrict__ bar, float* __restrict__ out)
{
    __shared__ f16 Wl[88 * 512];     // 90112B (>80KiB -> 1 wg/CU guaranteed)
    __shared__ int capS[SROWS][TT];
    __shared__ float scaleS[2];
    __shared__ unsigned idsS[20];
    __shared__ int fastpS;

    const int tid = threadIdx.x;
    const int b = blockIdx.x;
    const int grp = b & 7;
    const int idx = b >> 3;          // 0..29
    const int mrow0 = grp * 512;
    const int wv = tid >> 6, ln = tid & 63, c = ln & 15, kg = ln >> 4;

    unsigned* mfl = bar + grp * 1024;            // main flags at nb*32
    unsigned* gfl = bar + grp * 1024 + 640;      // helper flags at j*32
    unsigned* ids = bar + 8192 + grp * 32;       // 30 ids

    __builtin_amdgcn_fence(__ATOMIC_ACQUIRE, "agent");   // replay hygiene
    unsigned xcc;
    asm volatile("s_getreg_b32 %0, hwreg(HW_REG_XCC_ID)" : "=s"(xcc));
    const unsigned myid = xcc + 1u;
    if (tid == 0) {
        __hip_atomic_store(ids + idx, myid, __ATOMIC_RELAXED,
                           __HIP_MEMORY_SCOPE_AGENT);
        fastpS = 1;
    }

    // poll all main flags >= ph; optional acquire fence; wg barrier
    auto waitM = [&](unsigned ph, bool fen) {
        if (tid < NB) {
            while (__hip_atomic_load(mfl + tid * 32, __ATOMIC_RELAXED,
                                     __HIP_MEMORY_SCOPE_AGENT) < ph)
                __builtin_amdgcn_s_sleep(1);
        }
        if (fen) __builtin_amdgcn_fence(__ATOMIC_ACQUIRE, "agent");
        __syncthreads();
    };

    if (idx < NB) {
        // ========================= MAIN =========================
        const int nb = idx;
        const int owner = (nb <= 10) ? nb : nb - 11;
        unsigned* ghp = gfl + owner * 32;

        // Whh -> LDS frag-blocked: frag f = g*10+kt (40 x 1KB, conflict-free)
        for (int u = tid; u < 40 * 64; u += NTHR) {
            int f = u >> 6, l = u & 63;
            int g = f / KT, kt = f - g * KT;
            int jh0 = nb * 16 + (l & 15);
            int kb = kt * 32 + (l >> 4) * 8;
            f16x8 v;
            #pragma unroll
            for (int i = 0; i < 8; ++i) {
                int kk = kb + i;
                float x = (jh0 < 300 && kk < 300)
                          ? Whh[(size_t)(g * 300 + jh0) * 300 + kk] : 0.f;
                v[i] = (f16)x;
            }
            *(f16x8*)&Wl[(size_t)f * 512 + l * 8] = v;
        }
        const int srow0 = nb * SROWS;
        const int nr = (512 - srow0) < SROWS ? (512 - srow0) : SROWS;
        for (int u = tid; u < SROWS * TT; u += NTHR) {
            int rl = u / TT, t = u - rl * TT;
            if (rl < nr) capS[rl][t] = cap[(size_t)(mrow0 + srow0 + rl) * TT + t];
        }
        if (tid < 2) {
            float s = 0.f;
            for (int k = 0; k < 300; ++k) { float v = v_wn[tid * 300 + k]; s += v * v; }
            scaleS[tid] = g_wn[tid] * rsqrtf(s);
        }
        __syncthreads();

        auto stage_x = [&](int t) {
            f16* bufn = xb + (size_t)(t % XD) * HSLOT;
            for (int u = tid; u < nr * 40; u += NTHR) {
                int rl = u / 40, k8 = u - rl * 40;
                int grow = mrow0 + srow0 + rl;
                const float* er = embed + (size_t)capS[rl][t] * 300;
                int k0 = k8 * 8;
                f16x8 v;
                if (k0 < 296) {
                    v = pack8(*(const float4*)(er + k0), *(const float4*)(er + k0 + 4));
                } else if (k0 == 296) {
                    float4 a = *(const float4*)(er + 296);
                    v[0] = (f16)a.x; v[1] = (f16)a.y; v[2] = (f16)a.z; v[3] = (f16)a.w;
                    v[4] = v[5] = v[6] = v[7] = (f16)0.f;
                } else {
                    #pragma unroll
                    for (int i = 0; i < 8; ++i) v[i] = (f16)0.f;
                }
                size_t off = ((size_t)((grow >> 4) * KT + (k8 >> 2))) * 512
                             + (grow & 15) * 32 + (k8 & 3) * 8;
                *(f16x8*)(bufn + off) = v;
            }
        };

        // prologue: x(0..2) staged, covered by release flag 1
        stage_x(0); stage_x(1); stage_x(2);
        __syncthreads();
        if (tid == 0)
            __hip_atomic_store(mfl + nb * 32, 1u, __ATOMIC_RELEASE,
                               __HIP_MEMORY_SCOPE_AGENT);
        waitM(1, true);
        if (tid < NB)
            idsS[tid] = __hip_atomic_load(ids + tid, __ATOMIC_RELAXED,
                                          __HIP_MEMORY_SCOPE_AGENT);
        __syncthreads();

        // per-lane constants
        size_t aoff[4];
        #pragma unroll
        for (int m = 0; m < 4; ++m)
            aoff[m] = ((size_t)((mrow0 >> 4) + wv * 4 + m) * KT) * 512 + c * 32 + kg * 8;
        const int jh = nb * 16 + c;
        int lenr[4][4];
        #pragma unroll
        for (int m = 0; m < 4; ++m) {
            int rb = mrow0 + wv * 64 + m * 16 + kg * 4;
            #pragma unroll
            for (int rg = 0; rg < 4; ++rg) lenr[m][rg] = cap_len[rb + rg];
        }
        const int hkt = jh >> 5, hkgd = (jh >> 3) & 3, hel = jh & 7;
        size_t gxoff[4][4];
        #pragma unroll
        for (int m = 0; m < 4; ++m)
            #pragma unroll
            for (int g = 0; g < 4; ++g)
                gxoff[m][g] = ((((size_t)(grp * 19 + nb) * 4 + g) * 32
                               + (wv * 4 + m)) * 256) + ln * 4;

        float cst[4][4] = {};
        float hreg[4][4] = {};
        bool fastT = true;

        #pragma unroll 1
        for (int t = 0; t < STEPS; ++t) {
            // gx(t) wait (all threads poll one word)
            unsigned need = (unsigned)(t + 2);
            while (__hip_atomic_load(ghp, __ATOMIC_RELAXED,
                                     __HIP_MEMORY_SCOPE_AGENT) < need)
                __builtin_amdgcn_s_sleep(1);
            if (t == 0) {
                __builtin_amdgcn_fence(__ATOMIC_ACQUIRE, "agent");
                if (tid == 0) {
                    idsS[19] = __hip_atomic_load(ids + NB + owner, __ATOMIC_RELAXED,
                                                 __HIP_MEMORY_SCOPE_AGENT);
                    bool f = true;
                    for (int i = 0; i < 20; ++i) f = f && (idsS[i] == myid);
                    fastpS = f ? 1 : 0;
                }
            } else if (!fastpS) {
                __builtin_amdgcn_fence(__ATOMIC_ACQUIRE, "agent");
            }

            // acc = gx (bias folded by helper); nontemporal (GD-ring reuse)
            const f16* gxs = gxb + (size_t)(t % GD) * GXSLOT;
            f32x4 acc[4][4];
            #pragma unroll
            for (int m = 0; m < 4; ++m)
                #pragma unroll
                for (int g = 0; g < 4; ++g) {
                    f16x4 gv = __builtin_nontemporal_load(
                                   (const f16x4*)(gxs + gxoff[m][g]));
                    #pragma unroll
                    for (int rg = 0; rg < 4; ++rg) acc[m][g][rg] = (float)gv[rg];
                }

            if (t > 0) {
                bool fen = (t >= HD) || !fastpS;
                waitM((unsigned)(t + 1), fen);
                const f16* hs = hbuf + (size_t)(t % HD) * HSLOT;
                #pragma unroll
                for (int kt = 0; kt < KT; ++kt) {
                    f16x8 av[4];
                    #pragma unroll
                    for (int m = 0; m < 4; ++m)
                        av[m] = *(const f16x8*)(hs + aoff[m] + kt * 512);
                    #pragma unroll
                    for (int g = 0; g < 4; ++g) {
                        f16x8 bv = *(const f16x8*)&Wl[(size_t)(g * KT + kt) * 512 + ln * 8];
                        #pragma unroll
                        for (int m = 0; m < 4; ++m)
                            acc[m][g] = __builtin_amdgcn_mfma_f32_16x16x32_f16(av[m], bv, acc[m][g], 0, 0, 0);
                    }
                }
            }

            // gates + h(t+1) store (swizzled; garbage pads x Whh-pad-0 = 0)
            f16* hn = hbuf + (size_t)((t + 1) % HD) * HSLOT;
            #pragma unroll
            for (int m = 0; m < 4; ++m) {
                int rtile = (mrow0 >> 4) + wv * 4 + m;
                size_t hb0 = ((size_t)(rtile * KT + hkt)) * 512 + hkgd * 8 + hel;
                #pragma unroll
                for (int rg = 0; rg < 4; ++rg) {
                    bool upd = (t < lenr[m][rg]);
                    float iv = sigm(acc[m][0][rg]);
                    float fv = sigm(acc[m][1][rg]);
                    float gv = tanh_f(acc[m][2][rg]);
                    float ov = sigm(acc[m][3][rg]);
                    float cn = fv * cst[m][rg] + iv * gv;
                    cn = upd ? cn : cst[m][rg];
                    cst[m][rg] = cn;
                    float hnv = ov * tanh_f(cn);
                    hreg[m][rg] = upd ? hnv : hreg[m][rg];
                    f16 hv = (jh < 300) ? (f16)hreg[m][rg] : (f16)0.f;
                    hn[hb0 + (size_t)(kg * 4 + rg) * 32] = hv;
                }
            }

            __syncthreads();
            if (tid == 0) {
                fastT = (fastpS != 0);
                if (fastT)
                    __hip_atomic_store(mfl + nb * 32, (unsigned)(t + 2),
                                       __ATOMIC_RELAXED, __HIP_MEMORY_SCOPE_AGENT);
                else
                    __hip_atomic_store(mfl + nb * 32, (unsigned)(t + 2),
                                       __ATOMIC_RELEASE, __HIP_MEMORY_SCOPE_AGENT);
            }
            if (t + 3 < STEPS) stage_x(t + 3);   // off critical path
        }

        waitM((unsigned)(STEPS + 1), true);

        // head
        const f16* hs = hbuf + (size_t)(STEPS % HD) * HSLOT;
        for (int u = tid; u < nr * 2; u += NTHR) {
            int rl = u >> 1, cls = u & 1;
            int grow = mrow0 + srow0 + rl;
            float sc = scaleS[cls];
            const float* vr = v_wn + cls * 300;
            size_t rb = ((size_t)((grow >> 4) * KT)) * 512 + (grow & 15) * 32;
            float s = 0.f;
            #pragma unroll 4
            for (int k = 0; k < 300; ++k) {
                size_t off = rb + (size_t)(k >> 5) * 512 + ((k >> 3) & 3) * 8 + (k & 7);
                s += vr[k] * (float)hs[off];
            }
            out[(size_t)grow * 2 + cls] = sc * s + b_cls[cls];
        }
    } else {
        // ========================= HELPER =========================
        const int j = idx - NB;
        const int nt = (j < 8) ? 2 : 1;
        const int tiles[2] = { j, j + 11 };

        // Wih -> LDS frag-blocked: frag f = (tl*4+g)*10+kt
        for (int u = tid; u < nt * 40 * 64; u += NTHR) {
            int f = u >> 6, l = u & 63;
            int tl = f / 40, rest = f - tl * 40;
            int g = rest / KT, kt = rest - g * KT;
            int jh0 = tiles[tl] * 16 + (l & 15);
            int kb = kt * 32 + (l >> 4) * 8;
            f16x8 v;
            #pragma unroll
            for (int i = 0; i < 8; ++i) {
                int kk = kb + i;
                float x = (jh0 < 300 && kk < 300)
                          ? Wih[(size_t)(g * 300 + jh0) * 300 + kk] : 0.f;
                v[i] = (f16)x;
            }
            *(f16x8*)&Wl[(size_t)f * 512 + l * 8] = v;
        }
        float biasH[2][4];
        #pragma unroll
        for (int tl = 0; tl < 2; ++tl)
            #pragma unroll
            for (int g = 0; g < 4; ++g) {
                int jh0 = tiles[tl] * 16 + c;
                biasH[tl][g] = (tl < nt && jh0 < 300)
                               ? bih[g * 300 + jh0] + bhh[g * 300 + jh0] : 0.f;
            }
        size_t xoff[4];
        #pragma unroll
        for (int m = 0; m < 4; ++m)
            xoff[m] = ((size_t)((mrow0 >> 4) + wv * 4 + m) * KT) * 512 + c * 32 + kg * 8;
        __syncthreads();

        bool fastH = true;
        #pragma unroll 1
        for (int tw = 0; tw < STEPS; ++tw) {
            unsigned need = (tw < 1) ? 1u : (unsigned)tw;
            waitM(need, tw == 0 || !fastH);
            if (tw == 0) {
                if (tid < NB)
                    idsS[tid] = __hip_atomic_load(ids + tid, __ATOMIC_RELAXED,
                                                  __HIP_MEMORY_SCOPE_AGENT);
                __syncthreads();
                fastH = true;
                for (int i = 0; i < NB; ++i) fastH = fastH && (idsS[i] == myid);
            }

            const f16* xs = xb + (size_t)(tw % XD) * HSLOT;
            f16* gxs = gxb + (size_t)(tw % GD) * GXSLOT;

            f32x4 acc[4][2][4];
            #pragma unroll
            for (int m = 0; m < 4; ++m)
                #pragma unroll
                for (int tl = 0; tl < 2; ++tl)
                    #pragma unroll
                    for (int g = 0; g < 4; ++g) {
                        float bv = biasH[tl][g];
                        f32x4 b4 = {bv, bv, bv, bv};
                        acc[m][tl][g] = b4;
                    }

            #pragma unroll
            for (int kt = 0; kt < KT; ++kt) {
                f16x8 av[4];
                #pragma unroll
                for (int m = 0; m < 4; ++m)
                    av[m] = __builtin_nontemporal_load(
                                (const f16x8*)(xs + xoff[m] + kt * 512));
                #pragma unroll
                for (int tl = 0; tl < 2; ++tl) {
                    if (tl < nt) {
                        #pragma unroll
                        for (int g = 0; g < 4; ++g) {
                            f16x8 bv = *(const f16x8*)&Wl[(size_t)((tl * 4 + g) * KT + kt) * 512 + ln * 8];
                            #pragma unroll
                            for (int m = 0; m < 4; ++m)
                                acc[m][tl][g] = __builtin_amdgcn_mfma_f32_16x16x32_f16(av[m], bv, acc[m][tl][g], 0, 0, 0);
                        }
                    }
                }
            }

            #pragma unroll
            for (int m = 0; m < 4; ++m)
                #pragma unroll
                for (int tl = 0; tl < 2; ++tl) {
                    if (tl < nt) {
                        #pragma unroll
                        for (int g = 0; g < 4; ++g) {
                            f16x4 o;
                            #pragma unroll
                            for (int rg = 0; rg < 4; ++rg) o[rg] = (f16)acc[m][tl][g][rg];
                            size_t gi = ((((size_t)(grp * 19 + tiles[tl]) * 4 + g) * 32
                                          + (wv * 4 + m)) * 256) + ln * 4;
                            *(f16x4*)(gxs + gi) = o;
                        }
                    }
                }

            __syncthreads();
            if (tid == 0) {
                if (tw == 0 || !fastH)
                    __hip_atomic_store(gfl + j * 32, (unsigned)(tw + 2),
                                       __ATOMIC_RELEASE, __HIP_MEMORY_SCOPE_AGENT);
                else
                    __hip_atomic_store(gfl + j * 32, (unsigned)(tw + 2),
                                       __ATOMIC_RELAXED, __HIP_MEMORY_SCOPE_AGENT);
            }
        }
    }
}

extern "C" void kernel_launch(void* const* d_in, const int* in_sizes, int n_in,
                              void* d_out, int out_size, void* d_ws, size_t ws_size,
                              hipStream_t stream) {
    const int*   cap     = (const int*)  d_in[0];
    const int*   cap_len = (const int*)  d_in[1];
    const float* embed   = (const float*)d_in[2];
    const float* W_ih    = (const float*)d_in[3];
    const float* W_hh    = (const float*)d_in[4];
    const float* b_ih    = (const float*)d_in[5];
    const float* b_hh    = (const float*)d_in[6];
    const float* v_wn    = (const float*)d_in[7];
    const float* g_wn    = (const float*)d_in[8];
    const float* b_cls   = (const float*)d_in[9];
    float* out = (float*)d_out;

    unsigned* bar = (unsigned*)d_ws;
    f16* gxb  = (f16*)((char*)d_ws + 65536);
    f16* xb   = gxb + GD * GXSLOT;
    f16* hbuf = xb + XD * HSLOT;

    size_t fixed = 65536 + (GD * GXSLOT + XD * HSLOT) * 2;
    int HD = 2;
    if (ws_size > fixed) {
        size_t avail = (ws_size - fixed) / (HSLOT * 2);
        HD = (int)(avail > 23 ? 23 : avail);
        if (HD < 2) HD = 2;
    }

    hipMemsetAsync(bar, 0, 65536, stream);   // flags + ids only

    lstm_pc<<<NWG, NTHR, 0, stream>>>(cap, cap_len, embed, W_ih, W_hh,
                                      b_ih, b_hh, v_wn, g_wn, b_cls,
                                      gxb, xb, hbuf, HD, bar, out);
}